// Round 3
// baseline (436.152 us; speedup 1.0000x reference)
//
#include <hip/hip_runtime.h>
#include <math.h>

// Problem constants
static constexpr int Bv   = 8;
static constexpr int Nv   = 1024;
static constexpr int Cv   = 768;
static constexpr int Hv   = 12;
static constexpr int HIDv = 3072;
static constexpr int Mv   = Bv * Nv;   // 8192 rows

typedef __attribute__((ext_vector_type(4)))  float f32x4;
typedef __attribute__((ext_vector_type(16))) float f32x16;
typedef __attribute__((ext_vector_type(8)))  short s16x8;
typedef __attribute__((ext_vector_type(4)))  short s16x4;

__device__ __forceinline__ short f2bf(float f) {
  union { float f; unsigned u; } c; c.f = f;
  unsigned r = c.u + 0x7fffu + ((c.u >> 16) & 1u);   // RNE
  return (short)(r >> 16);
}

__device__ __forceinline__ void gload16(const void* g, void* l) {
  // async global->LDS, 16B per lane; LDS dest = wave-uniform base + lane*16
  __builtin_amdgcn_global_load_lds(
      (const __attribute__((address_space(1))) unsigned*)g,
      (__attribute__((address_space(3))) unsigned*)l, 16, 0, 0);
}

__device__ __forceinline__ unsigned ldsaddr(const void* p) {
  return (unsigned)(size_t)(const __attribute__((address_space(3))) char*)p;
}

__device__ __forceinline__ float fsigmoid_exp2(float t) {
  // returns 1/(1+2^t)
  return __builtin_amdgcn_rcpf(1.0f + __builtin_amdgcn_exp2f(t));
}

// ---------------- fp32 -> bf16 convert (weights) ----------------
__global__ __launch_bounds__(256) void cvt_kernel(const float* __restrict__ in,
                                                  short* __restrict__ out, int n4) {
  int i = blockIdx.x * 256 + threadIdx.x;
  if (i >= n4) return;
  float4 v = ((const float4*)in)[i];
  short4 o;
  o.x = f2bf(v.x); o.y = f2bf(v.y); o.z = f2bf(v.z); o.w = f2bf(v.w);
  ((short4*)out)[i] = o;
}

// ---------------- LayerNorm fp32 -> bf16 (one wave per row) ----------------
__global__ __launch_bounds__(256) void ln_kernel(const float* __restrict__ x,
                                                 const float* __restrict__ w,
                                                 const float* __restrict__ b,
                                                 short* __restrict__ out) {
  const int wv = threadIdx.x >> 6, l = threadIdx.x & 63;
  const int row = blockIdx.x * 4 + wv;
  const float4* xr = (const float4*)(x + (size_t)row * Cv);
  float4 v[3];
  float s = 0.f, s2 = 0.f;
#pragma unroll
  for (int c = 0; c < 3; ++c) {
    v[c] = xr[c * 64 + l];
    s  += v[c].x + v[c].y + v[c].z + v[c].w;
    s2 += v[c].x * v[c].x + v[c].y * v[c].y + v[c].z * v[c].z + v[c].w * v[c].w;
  }
#pragma unroll
  for (int o = 32; o; o >>= 1) { s += __shfl_xor(s, o); s2 += __shfl_xor(s2, o); }
  const float mu  = s * (1.f / Cv);
  const float var = s2 * (1.f / Cv) - mu * mu;
  const float rs  = rsqrtf(var + 1e-5f);
  short4* orow = (short4*)(out + (size_t)row * Cv);
  const float4* wp = (const float4*)w;
  const float4* bp = (const float4*)b;
#pragma unroll
  for (int c = 0; c < 3; ++c) {
    float4 wv4 = wp[c * 64 + l], bv4 = bp[c * 64 + l];
    short4 o4;
    o4.x = f2bf((v[c].x - mu) * rs * wv4.x + bv4.x);
    o4.y = f2bf((v[c].y - mu) * rs * wv4.y + bv4.y);
    o4.z = f2bf((v[c].z - mu) * rs * wv4.z + bv4.z);
    o4.w = f2bf((v[c].w - mu) * rs * wv4.w + bv4.w);
    orow[c * 64 + l] = o4;
  }
}

// ============ 256x256 ring-4 counted-vmcnt GEMM (T2+T3+T4+T5+T1) ============
// C[M,Nn] = A[M,K] @ Bw[Nn,K]^T. 512 thr = 8 waves (2Mx4N), per-wave 128x64.
// BK=32, LDS ring of 4 K-tiles (128 KiB). Stage tile kt+2 while computing kt;
// s_waitcnt vmcnt(4) per tile (never 0 until the tail).
// LDS layout per tile: [4 kb][256 rows][8 shorts] -> quarter-wave ds_read_b128
// is 256B contiguous (bank-conflict-free); gload dest linear 1KB regions.
// EPI: 0 = +bias -> bf16    2 = gelu(acc+bias) -> bf16
template <int EPI>
__global__ __launch_bounds__(512, 2) void gemm8p(const short* __restrict__ A,
                                                 const short* __restrict__ Bw,
                                                 int Nn, int K,
                                                 const float* __restrict__ bias,
                                                 short* __restrict__ outB) {
  __shared__ __align__(16) short ldsA[4][8192];
  __shared__ __align__(16) short ldsB[4][8192];
  const int tid = threadIdx.x, w = tid >> 6, l = tid & 63;
  const int nbx = Nn >> 8;
  const int cpx = (int)gridDim.x >> 3;
  const int wg = ((int)blockIdx.x & 7) * cpx + ((int)blockIdx.x >> 3);  // T1
  const int bx = wg % nbx, by = wg / nbx;
  const int rowBase = by << 8, colBase = bx << 8;
  const int nKt = K >> 5;
  const int wr = w >> 2, wc = w & 3;
  const int r0 = w, r1 = w + 8;                   // this wave's two 1KB regions

  f32x4 acc[8][4] = {};

  auto stageA = [&](int kt) {
    const int buf = kt & 3;
    const short* base = A + (size_t)rowBase * K + kt * 32;
    gload16(base + (size_t)((r0 & 3) * 64 + l) * K + (r0 >> 2) * 8, &ldsA[buf][r0 * 512]);
    gload16(base + (size_t)((r1 & 3) * 64 + l) * K + (r1 >> 2) * 8, &ldsA[buf][r1 * 512]);
  };
  auto stageB = [&](int kt) {
    const int buf = kt & 3;
    const short* base = Bw + (size_t)colBase * K + kt * 32;
    gload16(base + (size_t)((r0 & 3) * 64 + l) * K + (r0 >> 2) * 8, &ldsB[buf][r0 * 512]);
    gload16(base + (size_t)((r1 & 3) * 64 + l) * K + (r1 >> 2) * 8, &ldsB[buf][r1 * 512]);
  };

  // prologue: tiles 0 and 1 in flight; wait tile 0 (4 newest may remain)
  stageA(0); stageB(0); stageA(1); stageB(1);
  asm volatile("s_waitcnt vmcnt(4)" ::: "memory");
  __builtin_amdgcn_s_barrier();

  const int ao = (l >> 4) * 256 + wr * 128 + (l & 15);   // 16B-slot index
  const int bo = (l >> 4) * 256 + wc * 64 + (l & 15);

  for (int kt = 0; kt < nKt; ++kt) {
    const int buf = kt & 3;
    const short* la = &ldsA[buf][0];
    const short* lb = &ldsB[buf][0];
    s16x8 af[8], bfrag[4];
    // ---- phase 0: read A subtile + B cols 0-1, stage A(kt+2), MFMA half ----
#pragma unroll
    for (int rf = 0; rf < 8; ++rf)
      af[rf] = *(const s16x8*)(la + (size_t)(ao + rf * 16) * 8);
    bfrag[0] = *(const s16x8*)(lb + (size_t)(bo +  0) * 8);
    bfrag[1] = *(const s16x8*)(lb + (size_t)(bo + 16) * 8);
    if (kt + 2 < nKt) stageA(kt + 2);
    __builtin_amdgcn_s_barrier();
    __builtin_amdgcn_s_setprio(1);
#pragma unroll
    for (int rf = 0; rf < 8; ++rf) {
      acc[rf][0] = __builtin_amdgcn_mfma_f32_16x16x32_bf16(af[rf], bfrag[0], acc[rf][0], 0, 0, 0);
      acc[rf][1] = __builtin_amdgcn_mfma_f32_16x16x32_bf16(af[rf], bfrag[1], acc[rf][1], 0, 0, 0);
    }
    __builtin_amdgcn_s_setprio(0);
    __builtin_amdgcn_s_barrier();
    // ---- phase 1: read B cols 2-3, stage B(kt+2), MFMA other half ----
    bfrag[2] = *(const s16x8*)(lb + (size_t)(bo + 32) * 8);
    bfrag[3] = *(const s16x8*)(lb + (size_t)(bo + 48) * 8);
    if (kt + 2 < nKt) stageB(kt + 2);
    __builtin_amdgcn_s_barrier();
    __builtin_amdgcn_s_setprio(1);
#pragma unroll
    for (int rf = 0; rf < 8; ++rf) {
      acc[rf][2] = __builtin_amdgcn_mfma_f32_16x16x32_bf16(af[rf], bfrag[2], acc[rf][2], 0, 0, 0);
      acc[rf][3] = __builtin_amdgcn_mfma_f32_16x16x32_bf16(af[rf], bfrag[3], acc[rf][3], 0, 0, 0);
    }
    __builtin_amdgcn_s_setprio(0);
    // tile boundary: next tile's stages (issued 1 tile ago) must land in all
    // waves BEFORE anyone crosses the barrier -> vmcnt first, then barrier.
    if (kt + 2 < nKt) { asm volatile("s_waitcnt vmcnt(4)" ::: "memory"); }
    else              { asm volatile("s_waitcnt vmcnt(0)" ::: "memory"); }
    __builtin_amdgcn_s_barrier();
  }

  // epilogue: C/D col = lane&15, row = (lane>>4)*4 + r4
#pragma unroll
  for (int rf = 0; rf < 8; ++rf)
#pragma unroll
    for (int cf = 0; cf < 4; ++cf) {
      const int col = colBase + wc * 64 + cf * 16 + (l & 15);
      const float bcol = bias[col];
#pragma unroll
      for (int r4 = 0; r4 < 4; ++r4) {
        const int row = rowBase + wr * 128 + rf * 16 + (l >> 4) * 4 + r4;
        float v = acc[rf][cf][r4] + bcol;
        if (EPI == 2) v = v * fsigmoid_exp2(v * -2.4554669f);   // gelu approx
        outB[(size_t)row * Nn + col] = f2bf(v);
      }
    }
}

// ---------------- 128x128 GEMM (m97 structure) for proj / fc2 --------------
// EPI: 1 = resid + (acc+bias)*ls -> f32    3 = outF += (acc+bias)*ls
template <int EPI>
__global__ __launch_bounds__(256) void gemm_bt(const short* __restrict__ A,
                                               const short* __restrict__ Bw,
                                               int Nn, int K,
                                               const float* __restrict__ bias,
                                               const float* __restrict__ ls,
                                               const float* __restrict__ resid,
                                               float* __restrict__ outF) {
  __shared__ __align__(16) short ldsA[2][128 * 32];
  __shared__ __align__(16) short ldsB[2][128 * 32];
  const int tid = threadIdx.x, w = tid >> 6, l = tid & 63;
  const int nbx = Nn >> 7;
  const int cpx = (int)gridDim.x >> 3;
  const int wg = ((int)blockIdx.x & 7) * cpx + ((int)blockIdx.x >> 3);  // T1
  const int bx = wg % nbx, by = wg / nbx;
  const int rowBase = by << 7, colBase = bx << 7;
  const int nK = K >> 5;
  const int wr = w >> 1, wc = w & 1;
  const int lrow = l >> 2, lcb = (l & 3) * 8;

  f32x4 acc[4][4] = {};

  auto stage = [&](int buf, int kt) {
    const short* abase = A  + (size_t)rowBase * K + kt * 32;
    const short* bbase = Bw + (size_t)colBase * K + kt * 32;
#pragma unroll
    for (int i = 0; i < 2; ++i) {
      int r = w * 2 + i;
      gload16(abase + (size_t)(r * 16 + lrow) * K + lcb, &ldsA[buf][r * 512]);
      gload16(bbase + (size_t)(r * 16 + lrow) * K + lcb, &ldsB[buf][r * 512]);
    }
  };

  stage(0, 0);
  __syncthreads();
  int cur = 0;
  for (int kt = 0; kt < nK; ++kt) {
    if (kt + 1 < nK) stage(cur ^ 1, kt + 1);
    s16x8 af[4], bfr[4];
#pragma unroll
    for (int i = 0; i < 4; ++i) {
      af[i]  = *(const s16x8*)&ldsA[cur][(wr * 64 + i * 16 + (l & 15)) * 32 + (l >> 4) * 8];
      bfr[i] = *(const s16x8*)&ldsB[cur][(wc * 64 + i * 16 + (l & 15)) * 32 + (l >> 4) * 8];
    }
#pragma unroll
    for (int i = 0; i < 4; ++i)
#pragma unroll
      for (int j = 0; j < 4; ++j)
        acc[i][j] = __builtin_amdgcn_mfma_f32_16x16x32_bf16(af[i], bfr[j], acc[i][j], 0, 0, 0);
    __syncthreads();
    cur ^= 1;
  }

#pragma unroll
  for (int i = 0; i < 4; ++i)
#pragma unroll
    for (int j = 0; j < 4; ++j) {
      const int col = colBase + wc * 64 + j * 16 + (l & 15);
#pragma unroll
      for (int r4 = 0; r4 < 4; ++r4) {
        const int row = rowBase + wr * 64 + i * 16 + (l >> 4) * 4 + r4;
        float v = acc[i][j][r4];
        if (EPI == 1) {
          v = (v + bias[col]) * ls[col] + resid[(size_t)row * Nn + col];
          outF[(size_t)row * Nn + col] = v;
        } else {
          v = (v + bias[col]) * ls[col];
          outF[(size_t)row * Nn + col] += v;
        }
      }
    }
}

// ---------------- Sigmoid attention, swapped-operand 32x32 structure -------
__global__ __launch_bounds__(256) void attn_kernel(const short* __restrict__ qkv,
                                                   const float* __restrict__ pbias,
                                                   short* __restrict__ o) {
  __shared__ __align__(16) short ldsK[2][64 * 64];   // XOR-swizzled [kv][d]
  __shared__ __align__(16) short ldsV[2][64 * 64];   // subtiled [kv/4][d/16][4][16]
  const int tid = threadIdx.x, w = tid >> 6, l = tid & 63;
  const int qt = blockIdx.x & 7, bh = blockIdx.x >> 3;
  const int b = bh / Hv, h = bh % Hv;
  const int q0 = qt * 128;
  const float c1 = -0.125f * 1.44269504f;            // -scale*log2e
  const float c0 = -pbias[0] * 1.44269504f;          // = +10.0 for bias=-ln(1024)
  const size_t rstr = 3 * Cv;                        // 2304
  const short* qb = qkv + (size_t)b * Nv * rstr + h * 64;
  const short* kb = qb + Cv;
  const short* vb = qb + 2 * Cv;

  s16x8 qf[4];
  {
    const short* qrow = qb + (size_t)(q0 + w * 32 + (l & 31)) * rstr + (l >> 5) * 8;
#pragma unroll
    for (int dc = 0; dc < 4; ++dc) qf[dc] = *(const s16x8*)(qrow + dc * 16);
  }

  auto stage = [&](int buf, int t) {
#pragma unroll
    for (int i = 0; i < 2; ++i) {
      int r = w * 2 + i;
      int kv = r * 8 + (l >> 3);
      gload16(kb + (size_t)(t * 64 + kv) * rstr + (((l & 7) ^ (kv & 7)) << 3),
              &ldsK[buf][r * 512]);
      int s   = r * 8 + (l >> 3);
      int kv2 = ((s >> 2) << 2) + ((l & 7) >> 1);
      int d2  = ((s & 3) << 4) + ((l & 1) << 3);
      gload16(vb + (size_t)(t * 64 + kv2) * rstr + d2, &ldsV[buf][r * 512]);
    }
  };

  stage(0, 0);
  __syncthreads();

  f32x16 oacc[2] = {};
  int cur = 0;
  for (int t = 0; t < 16; ++t) {
    if (t + 1 < 16) stage(cur ^ 1, t + 1);

    f32x16 sacc[2] = {};
#pragma unroll
    for (int kvh = 0; kvh < 2; ++kvh) {
      const int kv = kvh * 32 + (l & 31);
#pragma unroll
      for (int dc = 0; dc < 4; ++dc) {
        s16x8 kf = *(const s16x8*)&ldsK[cur][kv * 64 + (((dc * 2 + (l >> 5)) ^ (kv & 7)) << 3)];
        sacc[kvh] = __builtin_amdgcn_mfma_f32_32x32x16_bf16(kf, qf[dc], sacc[kvh], 0, 0, 0);
      }
    }

    unsigned pw[4][4];
#pragma unroll
    for (int kvh = 0; kvh < 2; ++kvh) {
      float p[16];
#pragma unroll
      for (int r = 0; r < 16; ++r)
        p[r] = fsigmoid_exp2(sacc[kvh][r] * c1 + c0);
#pragma unroll
      for (int half = 0; half < 2; ++half) {
        const int c = kvh * 2 + half, rb = half * 8;
        unsigned a, bq, cc, dq;
        asm("v_cvt_pk_bf16_f32 %0,%1,%2" : "=v"(a)  : "v"(p[rb + 0]), "v"(p[rb + 1]));
        asm("v_cvt_pk_bf16_f32 %0,%1,%2" : "=v"(bq) : "v"(p[rb + 4]), "v"(p[rb + 5]));
        asm("v_cvt_pk_bf16_f32 %0,%1,%2" : "=v"(cc) : "v"(p[rb + 2]), "v"(p[rb + 3]));
        asm("v_cvt_pk_bf16_f32 %0,%1,%2" : "=v"(dq) : "v"(p[rb + 6]), "v"(p[rb + 7]));
        asm("v_permlane32_swap_b32 %0,%1" : "+v"(a),  "+v"(bq));
        asm("v_permlane32_swap_b32 %0,%1" : "+v"(cc), "+v"(dq));
        pw[c][0] = a; pw[c][1] = cc; pw[c][2] = bq; pw[c][3] = dq;
      }
    }

    const unsigned vlds = ldsaddr(&ldsV[cur][0]);
#pragma unroll
    for (int dt = 0; dt < 2; ++dt) {
      s16x4 t1[4], t2[4];
#pragma unroll
      for (int c = 0; c < 4; ++c) {
        int s1 = c * 16 + ((l >> 5) << 3) + dt * 2 + ((l >> 4) & 1);
        unsigned ad = vlds + (unsigned)(s1 * 128 + (l & 15) * 8);
        asm volatile("ds_read_b64_tr_b16 %0, %1"            : "=v"(t1[c]) : "v"(ad));
        asm volatile("ds_read_b64_tr_b16 %0, %1 offset:512" : "=v"(t2[c]) : "v"(ad));
      }
      asm volatile("s_waitcnt lgkmcnt(0)" ::: "memory");
      __builtin_amdgcn_sched_barrier(0);
#pragma unroll
      for (int c = 0; c < 4; ++c) {
        union { s16x4 q[2]; s16x8 v; } va;
        va.q[0] = t1[c]; va.q[1] = t2[c];
        union { unsigned u[4]; s16x8 v; } pb;
        pb.u[0] = pw[c][0]; pb.u[1] = pw[c][1]; pb.u[2] = pw[c][2]; pb.u[3] = pw[c][3];
        oacc[dt] = __builtin_amdgcn_mfma_f32_32x32x16_bf16(va.v, pb.v, oacc[dt], 0, 0, 0);
      }
    }

    __syncthreads();
    cur ^= 1;
  }

  __syncthreads();
  short* obuf = (short*)ldsK + w * 2048;
  {
    const int q = l & 31, hs = (l >> 5) << 3;
#pragma unroll
    for (int dt = 0; dt < 2; ++dt)
#pragma unroll
      for (int rg = 0; rg < 4; ++rg) {
        unsigned w0, w1;
        asm("v_cvt_pk_bf16_f32 %0,%1,%2" : "=v"(w0) : "v"(oacc[dt][rg * 4 + 0]), "v"(oacc[dt][rg * 4 + 1]));
        asm("v_cvt_pk_bf16_f32 %0,%1,%2" : "=v"(w1) : "v"(oacc[dt][rg * 4 + 2]), "v"(oacc[dt][rg * 4 + 3]));
        int slot = (dt * 4 + rg) ^ (q & 7);
        *(unsigned long long*)((char*)obuf + q * 128 + slot * 16 + hs) =
            (unsigned long long)w0 | ((unsigned long long)w1 << 32);
      }
  }
  __syncthreads();
  {
    const int q = l >> 1;
    const short* rrow = obuf + q * 64;
    short* orow = o + (size_t)(b * Nv + q0 + w * 32 + q) * Cv + h * 64 + (l & 1) * 32;
#pragma unroll
    for (int i = 0; i < 4; ++i) {
      int slot = (l & 1) * 4 + i;
      s16x8 vv = *(const s16x8*)(rrow + ((slot ^ (q & 7)) << 3));
      *(s16x8*)(orow + i * 8) = vv;
    }
  }
}

// ---------------- host launch ----------------
extern "C" void kernel_launch(void* const* d_in, const int* in_sizes, int n_in,
                              void* d_out, int out_size, void* d_ws, size_t ws_size,
                              hipStream_t stream) {
  const float* x      = (const float*)d_in[0];
  const float* ln1_w  = (const float*)d_in[1];
  const float* ln1_b  = (const float*)d_in[2];
  const float* qkv_w  = (const float*)d_in[3];
  const float* qkv_b  = (const float*)d_in[4];
  const float* proj_w = (const float*)d_in[5];
  const float* proj_b = (const float*)d_in[6];
  const float* attn_b = (const float*)d_in[7];
  const float* ls1    = (const float*)d_in[8];
  const float* ln2_w  = (const float*)d_in[9];
  const float* ln2_b  = (const float*)d_in[10];
  const float* w1     = (const float*)d_in[11];
  const float* b1     = (const float*)d_in[12];
  const float* w2     = (const float*)d_in[13];
  const float* b2     = (const float*)d_in[14];
  const float* ls2    = (const float*)d_in[15];
  float* out = (float*)d_out;

  char* ws = (char*)d_ws;
  short* wqkvb = (short*)ws;  ws += (size_t)3 * Cv * Cv * 2;
  short* wprjb = (short*)ws;  ws += (size_t)Cv * Cv * 2;
  short* w1b   = (short*)ws;  ws += (size_t)HIDv * Cv * 2;
  short* w2b   = (short*)ws;  ws += (size_t)Cv * HIDv * 2;
  short* bufA  = (short*)ws;  ws += (size_t)Mv * Cv * 2;      // h / o / h2
  short* bufB  = (short*)ws;                                  // qkv / m

  cvt_kernel<<<(3 * Cv * Cv / 4) / 256, 256, 0, stream>>>(qkv_w, wqkvb, 3 * Cv * Cv / 4);
  cvt_kernel<<<(Cv * Cv / 4) / 256, 256, 0, stream>>>(proj_w, wprjb, Cv * Cv / 4);
  cvt_kernel<<<(HIDv * Cv / 4) / 256, 256, 0, stream>>>(w1, w1b, HIDv * Cv / 4);
  cvt_kernel<<<(Cv * HIDv / 4) / 256, 256, 0, stream>>>(w2, w2b, Cv * HIDv / 4);

  ln_kernel<<<Mv / 4, 256, 0, stream>>>(x, ln1_w, ln1_b, bufA);
  // QKV: 256^2 ring-4 kernel (grid 32x9 = 288, %8==0)
  gemm8p<0><<<(Mv / 256) * (3 * Cv / 256), 512, 0, stream>>>(
      bufA, wqkvb, 3 * Cv, Cv, qkv_b, bufB);
  attn_kernel<<<Bv * Hv * (Nv / 128), 256, 0, stream>>>(bufB, attn_b, bufA);
  // proj + residual (128^2): grid 64x6 = 384
  gemm_bt<1><<<(Mv / 128) * (Cv / 128), 256, 0, stream>>>(
      bufA, wprjb, Cv, Cv, proj_b, ls1, x, out);
  ln_kernel<<<Mv / 4, 256, 0, stream>>>(out, ln2_w, ln2_b, bufA);
  // fc1 + gelu: 256^2 ring-4 (grid 32x12 = 384)
  gemm8p<2><<<(Mv / 256) * (HIDv / 256), 512, 0, stream>>>(
      bufA, w1b, HIDv, Cv, b1, bufB);
  // fc2 + residual (128^2): grid 64x6 = 384
  gemm_bt<3><<<(Mv / 128) * (Cv / 128), 256, 0, stream>>>(
      bufB, w2b, Cv, HIDv, b2, ls2, nullptr, out);
}

// Round 4
// 375.911 us; speedup vs baseline: 1.1603x; 1.1603x over previous
//
#include <hip/hip_runtime.h>
#include <math.h>

// Problem constants
static constexpr int Bv   = 8;
static constexpr int Nv   = 1024;
static constexpr int Cv   = 768;
static constexpr int Hv   = 12;
static constexpr int HIDv = 3072;
static constexpr int Mv   = Bv * Nv;   // 8192 rows

typedef __attribute__((ext_vector_type(4)))  float f32x4;
typedef __attribute__((ext_vector_type(16))) float f32x16;
typedef __attribute__((ext_vector_type(8)))  short s16x8;
typedef __attribute__((ext_vector_type(4)))  short s16x4;

__device__ __forceinline__ short f2bf(float f) {
  union { float f; unsigned u; } c; c.f = f;
  unsigned r = c.u + 0x7fffu + ((c.u >> 16) & 1u);   // RNE
  return (short)(r >> 16);
}

__device__ __forceinline__ void gload16(const void* g, void* l) {
  // async global->LDS, 16B per lane; LDS dest = wave-uniform base + lane*16
  __builtin_amdgcn_global_load_lds(
      (const __attribute__((address_space(1))) unsigned*)g,
      (__attribute__((address_space(3))) unsigned*)l, 16, 0, 0);
}

__device__ __forceinline__ unsigned ldsaddr(const void* p) {
  return (unsigned)(size_t)(const __attribute__((address_space(3))) char*)p;
}

__device__ __forceinline__ float fsigmoid_exp2(float t) {
  // returns 1/(1+2^t)
  return __builtin_amdgcn_rcpf(1.0f + __builtin_amdgcn_exp2f(t));
}

// ---------------- fused fp32 -> bf16 convert (all 4 weight tensors) --------
__global__ __launch_bounds__(256) void cvt4_kernel(const float* __restrict__ w0,
                                                   const float* __restrict__ w1,
                                                   const float* __restrict__ w2,
                                                   const float* __restrict__ w3,
                                                   short* __restrict__ o0,
                                                   short* __restrict__ o1,
                                                   short* __restrict__ o2,
                                                   short* __restrict__ o3) {
  // sizes in float4 units: 442368, 147456, 589824, 589824 (blocks of 256)
  int bid = blockIdx.x;
  const float* in; short* out; int i;
  if (bid < 1728)      { in = w0; out = o0; i = bid * 256 + threadIdx.x; }
  else if (bid < 2304) { in = w1; out = o1; i = (bid - 1728) * 256 + threadIdx.x; }
  else if (bid < 4608) { in = w2; out = o2; i = (bid - 2304) * 256 + threadIdx.x; }
  else                 { in = w3; out = o3; i = (bid - 4608) * 256 + threadIdx.x; }
  float4 v = ((const float4*)in)[i];
  short4 o;
  o.x = f2bf(v.x); o.y = f2bf(v.y); o.z = f2bf(v.z); o.w = f2bf(v.w);
  ((short4*)out)[i] = o;
}

// ---------------- LayerNorm fp32 -> bf16 (one wave per row) ----------------
__global__ __launch_bounds__(256) void ln_kernel(const float* __restrict__ x,
                                                 const float* __restrict__ w,
                                                 const float* __restrict__ b,
                                                 short* __restrict__ out) {
  const int wv = threadIdx.x >> 6, l = threadIdx.x & 63;
  const int row = blockIdx.x * 4 + wv;
  const float4* xr = (const float4*)(x + (size_t)row * Cv);
  float4 v[3];
  float s = 0.f, s2 = 0.f;
#pragma unroll
  for (int c = 0; c < 3; ++c) {
    v[c] = xr[c * 64 + l];
    s  += v[c].x + v[c].y + v[c].z + v[c].w;
    s2 += v[c].x * v[c].x + v[c].y * v[c].y + v[c].z * v[c].z + v[c].w * v[c].w;
  }
#pragma unroll
  for (int o = 32; o; o >>= 1) { s += __shfl_xor(s, o); s2 += __shfl_xor(s2, o); }
  const float mu  = s * (1.f / Cv);
  const float var = s2 * (1.f / Cv) - mu * mu;
  const float rs  = rsqrtf(var + 1e-5f);
  short4* orow = (short4*)(out + (size_t)row * Cv);
  const float4* wp = (const float4*)w;
  const float4* bp = (const float4*)b;
#pragma unroll
  for (int c = 0; c < 3; ++c) {
    float4 wv4 = wp[c * 64 + l], bv4 = bp[c * 64 + l];
    short4 o4;
    o4.x = f2bf((v[c].x - mu) * rs * wv4.x + bv4.x);
    o4.y = f2bf((v[c].y - mu) * rs * wv4.y + bv4.y);
    o4.z = f2bf((v[c].z - mu) * rs * wv4.z + bv4.z);
    o4.w = f2bf((v[c].w - mu) * rs * wv4.w + bv4.w);
    orow[c * 64 + l] = o4;
  }
}

// ---------------- 128x128 GEMM (m97 structure) for QKV / fc1 ---------------
// EPI: 0 = +bias -> bf16 out   2 = gelu(acc+bias) -> bf16
template <int EPI>
__global__ __launch_bounds__(256) void gemm_bt(const short* __restrict__ A,
                                               const short* __restrict__ Bw,
                                               int Nn, int K,
                                               const float* __restrict__ bias,
                                               short* __restrict__ outB) {
  __shared__ __align__(16) short ldsA[2][128 * 32];
  __shared__ __align__(16) short ldsB[2][128 * 32];
  const int tid = threadIdx.x, w = tid >> 6, l = tid & 63;
  const int nbx = Nn >> 7;
  const int cpx = (int)gridDim.x >> 3;
  const int wg = ((int)blockIdx.x & 7) * cpx + ((int)blockIdx.x >> 3);  // T1
  const int bx = wg % nbx, by = wg / nbx;
  const int rowBase = by << 7, colBase = bx << 7;
  const int nK = K >> 5;
  const int wr = w >> 1, wc = w & 1;
  const int lrow = l >> 2, lcb = (l & 3) * 8;

  f32x4 acc[4][4] = {};

  auto stage = [&](int buf, int kt) {
    const short* abase = A  + (size_t)rowBase * K + kt * 32;
    const short* bbase = Bw + (size_t)colBase * K + kt * 32;
#pragma unroll
    for (int i = 0; i < 2; ++i) {
      int r = w * 2 + i;
      gload16(abase + (size_t)(r * 16 + lrow) * K + lcb, &ldsA[buf][r * 512]);
      gload16(bbase + (size_t)(r * 16 + lrow) * K + lcb, &ldsB[buf][r * 512]);
    }
  };

  stage(0, 0);
  __syncthreads();
  int cur = 0;
  for (int kt = 0; kt < nK; ++kt) {
    if (kt + 1 < nK) stage(cur ^ 1, kt + 1);
    s16x8 af[4], bfr[4];
#pragma unroll
    for (int i = 0; i < 4; ++i) {
      af[i]  = *(const s16x8*)&ldsA[cur][(wr * 64 + i * 16 + (l & 15)) * 32 + (l >> 4) * 8];
      bfr[i] = *(const s16x8*)&ldsB[cur][(wc * 64 + i * 16 + (l & 15)) * 32 + (l >> 4) * 8];
    }
#pragma unroll
    for (int i = 0; i < 4; ++i)
#pragma unroll
      for (int j = 0; j < 4; ++j)
        acc[i][j] = __builtin_amdgcn_mfma_f32_16x16x32_bf16(af[i], bfr[j], acc[i][j], 0, 0, 0);
    __syncthreads();
    cur ^= 1;
  }

#pragma unroll
  for (int i = 0; i < 4; ++i)
#pragma unroll
    for (int j = 0; j < 4; ++j) {
      const int col = colBase + wc * 64 + j * 16 + (l & 15);
      const float bcol = bias[col];
#pragma unroll
      for (int r4 = 0; r4 < 4; ++r4) {
        const int row = rowBase + wr * 64 + i * 16 + (l >> 4) * 4 + r4;
        float v = acc[i][j][r4] + bcol;
        if (EPI == 2) v = v * fsigmoid_exp2(v * -2.4554669f);   // gelu approx
        outB[(size_t)row * Nn + col] = f2bf(v);
      }
    }
}

// ---------------- 64x128 GEMM (m97 structure) for proj / fc2 ---------------
// Thin-N shapes: 768 blocks -> ~3 blocks/CU for latency hiding.
// EPI: 1 = resid + (acc+bias)*ls -> f32    3 = outF += (acc+bias)*ls
template <int EPI>
__global__ __launch_bounds__(256) void gemm_sm(const short* __restrict__ A,
                                               const short* __restrict__ Bw,
                                               int Nn, int K,
                                               const float* __restrict__ bias,
                                               const float* __restrict__ ls,
                                               const float* __restrict__ resid,
                                               float* __restrict__ outF) {
  __shared__ __align__(16) short ldsA[2][64 * 32];
  __shared__ __align__(16) short ldsB[2][128 * 32];
  const int tid = threadIdx.x, w = tid >> 6, l = tid & 63;
  const int nbx = Nn >> 7;
  const int cpx = (int)gridDim.x >> 3;
  const int wg = ((int)blockIdx.x & 7) * cpx + ((int)blockIdx.x >> 3);  // T1
  const int bx = wg % nbx, by = wg / nbx;
  const int rowBase = by << 6, colBase = bx << 7;
  const int nK = K >> 5;
  const int wr = w >> 1, wc = w & 1;
  const int lrow = l >> 2, lcb = (l & 3) * 8;

  f32x4 acc[2][4] = {};

  auto stage = [&](int buf, int kt) {
    const short* abase = A  + (size_t)rowBase * K + kt * 32;
    const short* bbase = Bw + (size_t)colBase * K + kt * 32;
    // A: 4 regions (wave w does region w); B: 8 regions (wave w does w*2, w*2+1)
    gload16(abase + (size_t)(w * 16 + lrow) * K + lcb, &ldsA[buf][w * 512]);
#pragma unroll
    for (int i = 0; i < 2; ++i) {
      int r = w * 2 + i;
      gload16(bbase + (size_t)(r * 16 + lrow) * K + lcb, &ldsB[buf][r * 512]);
    }
  };

  stage(0, 0);
  __syncthreads();
  int cur = 0;
  for (int kt = 0; kt < nK; ++kt) {
    if (kt + 1 < nK) stage(cur ^ 1, kt + 1);
    s16x8 af[2], bfr[4];
#pragma unroll
    for (int i = 0; i < 2; ++i)
      af[i]  = *(const s16x8*)&ldsA[cur][(wr * 32 + i * 16 + (l & 15)) * 32 + (l >> 4) * 8];
#pragma unroll
    for (int j = 0; j < 4; ++j)
      bfr[j] = *(const s16x8*)&ldsB[cur][(wc * 64 + j * 16 + (l & 15)) * 32 + (l >> 4) * 8];
#pragma unroll
    for (int i = 0; i < 2; ++i)
#pragma unroll
      for (int j = 0; j < 4; ++j)
        acc[i][j] = __builtin_amdgcn_mfma_f32_16x16x32_bf16(af[i], bfr[j], acc[i][j], 0, 0, 0);
    __syncthreads();
    cur ^= 1;
  }

#pragma unroll
  for (int i = 0; i < 2; ++i)
#pragma unroll
    for (int j = 0; j < 4; ++j) {
      const int col = colBase + wc * 64 + j * 16 + (l & 15);
      const float bcol = bias[col], lscol = ls[col];
#pragma unroll
      for (int r4 = 0; r4 < 4; ++r4) {
        const int row = rowBase + wr * 32 + i * 16 + (l >> 4) * 4 + r4;
        float v = (acc[i][j][r4] + bcol) * lscol;
        if (EPI == 1) {
          outF[(size_t)row * Nn + col] = v + resid[(size_t)row * Nn + col];
        } else {
          outF[(size_t)row * Nn + col] += v;
        }
      }
    }
}

// ---------------- Sigmoid attention, swapped-operand 32x32 structure -------
__global__ __launch_bounds__(256) void attn_kernel(const short* __restrict__ qkv,
                                                   const float* __restrict__ pbias,
                                                   short* __restrict__ o) {
  __shared__ __align__(16) short ldsK[2][64 * 64];   // XOR-swizzled [kv][d]
  __shared__ __align__(16) short ldsV[2][64 * 64];   // subtiled [kv/4][d/16][4][16]
  const int tid = threadIdx.x, w = tid >> 6, l = tid & 63;
  const int qt = blockIdx.x & 7, bh = blockIdx.x >> 3;
  const int b = bh / Hv, h = bh % Hv;
  const int q0 = qt * 128;
  const float c1 = -0.125f * 1.44269504f;            // -scale*log2e
  const float c0 = -pbias[0] * 1.44269504f;          // = +10.0 for bias=-ln(1024)
  const size_t rstr = 3 * Cv;                        // 2304
  const short* qb = qkv + (size_t)b * Nv * rstr + h * 64;
  const short* kb = qb + Cv;
  const short* vb = qb + 2 * Cv;

  s16x8 qf[4];
  {
    const short* qrow = qb + (size_t)(q0 + w * 32 + (l & 31)) * rstr + (l >> 5) * 8;
#pragma unroll
    for (int dc = 0; dc < 4; ++dc) qf[dc] = *(const s16x8*)(qrow + dc * 16);
  }

  auto stage = [&](int buf, int t) {
#pragma unroll
    for (int i = 0; i < 2; ++i) {
      int r = w * 2 + i;
      int kv = r * 8 + (l >> 3);
      gload16(kb + (size_t)(t * 64 + kv) * rstr + (((l & 7) ^ (kv & 7)) << 3),
              &ldsK[buf][r * 512]);
      int s   = r * 8 + (l >> 3);
      int kv2 = ((s >> 2) << 2) + ((l & 7) >> 1);
      int d2  = ((s & 3) << 4) + ((l & 1) << 3);
      gload16(vb + (size_t)(t * 64 + kv2) * rstr + d2, &ldsV[buf][r * 512]);
    }
  };

  stage(0, 0);
  __syncthreads();

  f32x16 oacc[2] = {};
  int cur = 0;
  for (int t = 0; t < 16; ++t) {
    if (t + 1 < 16) stage(cur ^ 1, t + 1);

    f32x16 sacc[2] = {};
#pragma unroll
    for (int kvh = 0; kvh < 2; ++kvh) {
      const int kv = kvh * 32 + (l & 31);
#pragma unroll
      for (int dc = 0; dc < 4; ++dc) {
        s16x8 kf = *(const s16x8*)&ldsK[cur][kv * 64 + (((dc * 2 + (l >> 5)) ^ (kv & 7)) << 3)];
        sacc[kvh] = __builtin_amdgcn_mfma_f32_32x32x16_bf16(kf, qf[dc], sacc[kvh], 0, 0, 0);
      }
    }

    unsigned pw[4][4];
#pragma unroll
    for (int kvh = 0; kvh < 2; ++kvh) {
      float p[16];
#pragma unroll
      for (int r = 0; r < 16; ++r)
        p[r] = fsigmoid_exp2(sacc[kvh][r] * c1 + c0);
#pragma unroll
      for (int half = 0; half < 2; ++half) {
        const int c = kvh * 2 + half, rb = half * 8;
        unsigned a, bq, cc, dq;
        asm("v_cvt_pk_bf16_f32 %0,%1,%2" : "=v"(a)  : "v"(p[rb + 0]), "v"(p[rb + 1]));
        asm("v_cvt_pk_bf16_f32 %0,%1,%2" : "=v"(bq) : "v"(p[rb + 4]), "v"(p[rb + 5]));
        asm("v_cvt_pk_bf16_f32 %0,%1,%2" : "=v"(cc) : "v"(p[rb + 2]), "v"(p[rb + 3]));
        asm("v_cvt_pk_bf16_f32 %0,%1,%2" : "=v"(dq) : "v"(p[rb + 6]), "v"(p[rb + 7]));
        asm("v_permlane32_swap_b32 %0,%1" : "+v"(a),  "+v"(bq));
        asm("v_permlane32_swap_b32 %0,%1" : "+v"(cc), "+v"(dq));
        pw[c][0] = a; pw[c][1] = cc; pw[c][2] = bq; pw[c][3] = dq;
      }
    }

    const unsigned vlds = ldsaddr(&ldsV[cur][0]);
#pragma unroll
    for (int dt = 0; dt < 2; ++dt) {
      s16x4 t1[4], t2[4];
#pragma unroll
      for (int c = 0; c < 4; ++c) {
        int s1 = c * 16 + ((l >> 5) << 3) + dt * 2 + ((l >> 4) & 1);
        unsigned ad = vlds + (unsigned)(s1 * 128 + (l & 15) * 8);
        asm volatile("ds_read_b64_tr_b16 %0, %1"            : "=v"(t1[c]) : "v"(ad));
        asm volatile("ds_read_b64_tr_b16 %0, %1 offset:512" : "=v"(t2[c]) : "v"(ad));
      }
      asm volatile("s_waitcnt lgkmcnt(0)" ::: "memory");
      __builtin_amdgcn_sched_barrier(0);
#pragma unroll
      for (int c = 0; c < 4; ++c) {
        union { s16x4 q[2]; s16x8 v; } va;
        va.q[0] = t1[c]; va.q[1] = t2[c];
        union { unsigned u[4]; s16x8 v; } pb;
        pb.u[0] = pw[c][0]; pb.u[1] = pw[c][1]; pb.u[2] = pw[c][2]; pb.u[3] = pw[c][3];
        oacc[dt] = __builtin_amdgcn_mfma_f32_32x32x16_bf16(va.v, pb.v, oacc[dt], 0, 0, 0);
      }
    }

    __syncthreads();
    cur ^= 1;
  }

  __syncthreads();
  short* obuf = (short*)ldsK + w * 2048;
  {
    const int q = l & 31, hs = (l >> 5) << 3;
#pragma unroll
    for (int dt = 0; dt < 2; ++dt)
#pragma unroll
      for (int rg = 0; rg < 4; ++rg) {
        unsigned w0, w1;
        asm("v_cvt_pk_bf16_f32 %0,%1,%2" : "=v"(w0) : "v"(oacc[dt][rg * 4 + 0]), "v"(oacc[dt][rg * 4 + 1]));
        asm("v_cvt_pk_bf16_f32 %0,%1,%2" : "=v"(w1) : "v"(oacc[dt][rg * 4 + 2]), "v"(oacc[dt][rg * 4 + 3]));
        int slot = (dt * 4 + rg) ^ (q & 7);
        *(unsigned long long*)((char*)obuf + q * 128 + slot * 16 + hs) =
            (unsigned long long)w0 | ((unsigned long long)w1 << 32);
      }
  }
  __syncthreads();
  {
    const int q = l >> 1;
    const short* rrow = obuf + q * 64;
    short* orow = o + (size_t)(b * Nv + q0 + w * 32 + q) * Cv + h * 64 + (l & 1) * 32;
#pragma unroll
    for (int i = 0; i < 4; ++i) {
      int slot = (l & 1) * 4 + i;
      s16x8 vv = *(const s16x8*)(rrow + ((slot ^ (q & 7)) << 3));
      *(s16x8*)(orow + i * 8) = vv;
    }
  }
}

// ---------------- host launch ----------------
extern "C" void kernel_launch(void* const* d_in, const int* in_sizes, int n_in,
                              void* d_out, int out_size, void* d_ws, size_t ws_size,
                              hipStream_t stream) {
  const float* x      = (const float*)d_in[0];
  const float* ln1_w  = (const float*)d_in[1];
  const float* ln1_b  = (const float*)d_in[2];
  const float* qkv_w  = (const float*)d_in[3];
  const float* qkv_b  = (const float*)d_in[4];
  const float* proj_w = (const float*)d_in[5];
  const float* proj_b = (const float*)d_in[6];
  const float* attn_b = (const float*)d_in[7];
  const float* ls1    = (const float*)d_in[8];
  const float* ln2_w  = (const float*)d_in[9];
  const float* ln2_b  = (const float*)d_in[10];
  const float* w1     = (const float*)d_in[11];
  const float* b1     = (const float*)d_in[12];
  const float* w2     = (const float*)d_in[13];
  const float* b2     = (const float*)d_in[14];
  const float* ls2    = (const float*)d_in[15];
  float* out = (float*)d_out;

  char* ws = (char*)d_ws;
  short* wqkvb = (short*)ws;  ws += (size_t)3 * Cv * Cv * 2;
  short* wprjb = (short*)ws;  ws += (size_t)Cv * Cv * 2;
  short* w1b   = (short*)ws;  ws += (size_t)HIDv * Cv * 2;
  short* w2b   = (short*)ws;  ws += (size_t)Cv * HIDv * 2;
  short* bufA  = (short*)ws;  ws += (size_t)Mv * Cv * 2;      // h / o / h2
  short* bufB  = (short*)ws;                                  // qkv / m

  cvt4_kernel<<<6912, 256, 0, stream>>>(qkv_w, proj_w, w1, w2,
                                        wqkvb, wprjb, w1b, w2b);

  ln_kernel<<<Mv / 4, 256, 0, stream>>>(x, ln1_w, ln1_b, bufA);
  // QKV (128^2): grid 64x18 = 1152
  gemm_bt<0><<<(Mv / 128) * (3 * Cv / 128), 256, 0, stream>>>(
      bufA, wqkvb, 3 * Cv, Cv, qkv_b, bufB);
  attn_kernel<<<Bv * Hv * (Nv / 128), 256, 0, stream>>>(bufB, attn_b, bufA);
  // proj + residual (64x128): grid 128x6 = 768
  gemm_sm<1><<<(Mv / 64) * (Cv / 128), 256, 0, stream>>>(
      bufA, wprjb, Cv, Cv, proj_b, ls1, x, out);
  ln_kernel<<<Mv / 4, 256, 0, stream>>>(out, ln2_w, ln2_b, bufA);
  // fc1 + gelu (128^2): grid 64x24 = 1536
  gemm_bt<2><<<(Mv / 128) * (HIDv / 128), 256, 0, stream>>>(
      bufA, w1b, HIDv, Cv, b1, bufB);
  // fc2 + residual (64x128): grid 128x6 = 768
  gemm_sm<3><<<(Mv / 64) * (Cv / 128), 256, 0, stream>>>(
      bufB, w2b, Cv, HIDv, b2, ls2, nullptr, out);
}